// Round 9
// baseline (745.273 us; speedup 1.0000x reference)
//
#include <hip/hip_runtime.h>

// Seq2Seq LSTM (enc 512 + dec 256 steps), H=50, B=2048, in/out dim 1.
//
// Round-9: ONE WAVE = TWO batch elements, sharing the same 200 register-
// resident weights (weights are batch-invariant -- every previous round
// paid the full 200-reg cost per element). Grid = 1024 blocks of 64 thr =
// exactly 1 wave/SIMD; the two independent element streams give in-wave ILP
// that hides ds_read latency (r8 idled 32% with 2 lock-step waves/SIMD).
// __launch_bounds__(64,1): 512-reg budget, live set ~250.
//
// Weight multiplies stay inline-asm v_pk_fma_f32 ("v" constraints keep the
// operands in arch VGPRs -- r8 proved this beats compiler AGPR parking).
// log2(e) is folded into all gate weights/biases (gate g gets 2*log2e for
// tanh = 2*sigm(2x)-1), so every activation is rcp(1+exp2(-a)): no v_mul
// per __expf. tanh(c) keeps its explicit scale (c is in linear domain).
//
// Step: 26 broadcast ds_read_b128 (13/element, conflict-free), 208 pk_fma,
// 10 exp2 + 10 rcp, h writes + 1 (single-wave, cheap) barrier. Decoder y
// via two interleaved 6-shfl butterflies, fed back as next x.

#define HID 50
#define SEQ 512
#define TGT 256

typedef float v2f __attribute__((ext_vector_type(2)));

#define L2E 1.44269504088896341f

// Packed FMA with arch-VGPR-forcing constraints: acc += w * h (2 floats).
#define PKFMA(acc, w, h) \
    asm("v_pk_fma_f32 %0, %1, %2, %0" : "+v"(acc) : "v"(w), "v"(h))

// sigmoid in log2 domain: a is pre-scaled by log2(e).
__device__ __forceinline__ float sigm2(v2f a) {
    float s = a.x + a.y;
    return __builtin_amdgcn_rcpf(1.0f + __builtin_amdgcn_exp2f(-s));
}
__device__ __forceinline__ float tanhc(float c) {   // tanh of linear-domain c
    return fmaf(2.0f,
        __builtin_amdgcn_rcpf(1.0f + __builtin_amdgcn_exp2f(-2.0f * L2E * c)),
        -1.0f);
}

// Load the lane's 4 gate rows of W_hh as 25 v2f each, pre-scaled by
// log2e (2*log2e for gate 2 = tanh); same for wx and summed bias.
#define LOAD_W(Wih, Whh, Bih, Bhh)                                    \
    {                                                                 \
        _Pragma("unroll")                                             \
        for (int g = 0; g < 4; ++g) {                                 \
            const float sc_ = (g == 2) ? 2.0f * L2E : L2E;            \
            const v2f* r2 = (const v2f*)((Whh) + (size_t)(g * HID + u) * HID); \
            _Pragma("unroll")                                         \
            for (int p = 0; p < 25; ++p) {                            \
                v2f t_ = r2[p];                                       \
                wg[g][p] = (v2f){t_.x * sc_, t_.y * sc_};             \
            }                                                         \
            wx[g] = (Wih)[g * HID + u] * sc_;                         \
            bb[g] = ((Bih)[g * HID + u] + (Bhh)[g * HID + u]) * sc_;  \
        }                                                             \
    }

// One dual-element LSTM step. Reads hInA/hInB (52 floats each, pads 0),
// writes hOutA/hOutB; defines hnA,hnB; updates cA,cB. No barrier inside.
#define STEP2(xvA, xvB, hInA, hInB, hOutA, hOutB)                     \
    float hnA, hnB;                                                   \
    {                                                                 \
        const float4* hA4_ = (const float4*)(hInA);                   \
        const float4* hB4_ = (const float4*)(hInB);                   \
        v2f aA[4], aB[4];                                             \
        _Pragma("unroll")                                             \
        for (int g = 0; g < 4; ++g) {                                 \
            aA[g] = (v2f){bb[g], wx[g] * (xvA)};                      \
            aB[g] = (v2f){bb[g], wx[g] * (xvB)};                      \
        }                                                             \
        _Pragma("unroll")                                             \
        for (int q = 0; q < 12; ++q) {                                \
            float4 ha_ = hA4_[q];                                     \
            float4 hb_ = hB4_[q];                                     \
            v2f haxy = {ha_.x, ha_.y}, hazw = {ha_.z, ha_.w};         \
            v2f hbxy = {hb_.x, hb_.y}, hbzw = {hb_.z, hb_.w};         \
            _Pragma("unroll")                                         \
            for (int g = 0; g < 4; ++g) {                             \
                PKFMA(aA[g], wg[g][2 * q], haxy);                     \
                PKFMA(aB[g], wg[g][2 * q], hbxy);                     \
                PKFMA(aA[g], wg[g][2 * q + 1], hazw);                 \
                PKFMA(aB[g], wg[g][2 * q + 1], hbzw);                 \
            }                                                         \
        }                                                             \
        {   /* pair 24: k = 48,49 (only .xy of quad 12 is real) */    \
            float4 ha_ = hA4_[12];                                    \
            float4 hb_ = hB4_[12];                                    \
            v2f haxy = {ha_.x, ha_.y};                                \
            v2f hbxy = {hb_.x, hb_.y};                                \
            _Pragma("unroll")                                         \
            for (int g = 0; g < 4; ++g) {                             \
                PKFMA(aA[g], wg[g][24], haxy);                        \
                PKFMA(aB[g], wg[g][24], hbxy);                        \
            }                                                         \
        }                                                             \
        float giA = sigm2(aA[0]), giB = sigm2(aB[0]);                 \
        float gfA = sigm2(aA[1]), gfB = sigm2(aB[1]);                 \
        float ggA = fmaf(2.0f, sigm2(aA[2]), -1.0f);                  \
        float ggB = fmaf(2.0f, sigm2(aB[2]), -1.0f);                  \
        float goA = sigm2(aA[3]), goB = sigm2(aB[3]);                 \
        cA = fmaf(gfA, cA, giA * ggA);                                \
        cB = fmaf(gfB, cB, giB * ggB);                                \
        hnA = goA * tanhc(cA);                                        \
        hnB = goB * tanhc(cB);                                        \
        if (act) { (hOutA)[j] = hnA; (hOutB)[j] = hnB; }              \
    }

extern "C" __global__ void __launch_bounds__(64, 1)
seq2seq_kernel(const float* __restrict__ src,
               const float* __restrict__ eWih, const float* __restrict__ eWhh,
               const float* __restrict__ eBih, const float* __restrict__ eBhh,
               const float* __restrict__ dWih, const float* __restrict__ dWhh,
               const float* __restrict__ dBih, const float* __restrict__ dBhh,
               const float* __restrict__ fcW, const float* __restrict__ fcB,
               float* __restrict__ out) {
    const int b = blockIdx.x;                   // handles elements 2b, 2b+1
    const int j = threadIdx.x;                  // lane 0..63
    const bool act = (j < HID);
    const int u = act ? j : (HID - 1);          // clamped unit id

    __shared__ __align__(16) float hA0[52], hA1[52], hB0[52], hB1[52];
    if (j < 52) { hA0[j] = 0.0f; hA1[j] = 0.0f; hB0[j] = 0.0f; hB1[j] = 0.0f; }
    __syncthreads();

    v2f wg[4][25];                              // 200 shared weight VGPRs
    float wx[4], bb[4];
    float cA = 0.0f, cB = 0.0f;

    // ---------------- encoder: 512 steps (unrolled x2) ----------------
    LOAD_W(eWih, eWhh, eBih, eBhh);
    const float* sbA = src + (size_t)(2 * b) * SEQ;
    const float* sbB = sbA + SEQ;
    float xA = sbA[0], xB = sbB[0];
    for (int t = 0; t < SEQ; t += 2) {
        float xA1 = sbA[t + 1], xB1 = sbB[t + 1];            // prefetch
        float xA2 = (t + 2 < SEQ) ? sbA[t + 2] : 0.0f;
        float xB2 = (t + 2 < SEQ) ? sbB[t + 2] : 0.0f;
        { STEP2(xA, xB, hA0, hB0, hA1, hB1) }
        __syncthreads();
        { STEP2(xA1, xB1, hA1, hB1, hA0, hB0) }
        __syncthreads();
        xA = xA2; xB = xB2;
    }
    // state now in hA0 / hB0

    // ---------------- decoder: 256 steps (unrolled x2) ----------------
    LOAD_W(dWih, dWhh, dBih, dBhh);
    const float fw = act ? fcW[u] : 0.0f;       // lanes 50-63 contribute 0
    const float fb = fcB[0];
    float* obA = out + (size_t)(2 * b) * TGT;
    float* obB = obA + TGT;

    xA = 0.0f; xB = 0.0f;                       // decoder_input = zeros
    for (int t = 0; t < TGT; t += 2) {
        {
            STEP2(xA, xB, hA0, hB0, hA1, hB1)
            float pA = fw * hnA, pB = fw * hnB;
#pragma unroll
            for (int off = 32; off > 0; off >>= 1) {
                pA += __shfl_xor(pA, off, 64);
                pB += __shfl_xor(pB, off, 64);
            }
            float yA = pA + fb, yB = pB + fb;   // every lane has y
            if (j == 0) { obA[t] = yA; obB[t] = yB; }
            xA = yA; xB = yB;
        }
        __syncthreads();
        {
            STEP2(xA, xB, hA1, hB1, hA0, hB0)
            float pA = fw * hnA, pB = fw * hnB;
#pragma unroll
            for (int off = 32; off > 0; off >>= 1) {
                pA += __shfl_xor(pA, off, 64);
                pB += __shfl_xor(pB, off, 64);
            }
            float yA = pA + fb, yB = pB + fb;
            if (j == 0) { obA[t + 1] = yA; obB[t + 1] = yB; }
            xA = yA; xB = yB;
        }
        __syncthreads();
    }
}

extern "C" void kernel_launch(void* const* d_in, const int* in_sizes, int n_in,
                              void* d_out, int out_size, void* d_ws, size_t ws_size,
                              hipStream_t stream) {
    const float* src  = (const float*)d_in[0];
    const float* eWih = (const float*)d_in[1];
    const float* eWhh = (const float*)d_in[2];
    const float* eBih = (const float*)d_in[3];
    const float* eBhh = (const float*)d_in[4];
    const float* dWih = (const float*)d_in[5];
    const float* dWhh = (const float*)d_in[6];
    const float* dBih = (const float*)d_in[7];
    const float* dBhh = (const float*)d_in[8];
    const float* fcW  = (const float*)d_in[9];
    const float* fcB  = (const float*)d_in[10];
    float* out = (float*)d_out;

    const int B = in_sizes[0] / SEQ;            // 2048
    seq2seq_kernel<<<B / 2, 64, 0, stream>>>(src, eWih, eWhh, eBih, eBhh,
                                             dWih, dWhh, dBih, dBhh,
                                             fcW, fcB, out);
}